// Round 3
// baseline (13316.869 us; speedup 1.0000x reference)
//
#include <hip/hip_runtime.h>
#include <hip/hip_bf16.h>
#include <hip/hip_cooperative_groups.h>

namespace cg = cooperative_groups;

typedef __hip_bfloat16 bf16;
typedef __attribute__((ext_vector_type(8))) short s16x8;   // 8 bf16 = 4 VGPRs (MFMA A/B frag)
typedef __attribute__((ext_vector_type(4))) float f32x4;   // MFMA C/D frag

#define BATCH   64
#define SEQ     256
#define HID     1024
#define GATES   4096
#define NWG     256
#define THREADS 256
#define UNITS   8            // hidden units per WG
#define NCOLS   32           // gate columns per WG (4 gates x 8 units)
#define ROWSTRIDE 2056       // 2048 K + 8 pad elems -> breaks LDS bank aliasing
#define BH      (BATCH * HID)

#define OUT_HN  ((size_t)BATCH * SEQ * HID)          // 16,777,216
#define OUT_CN  (OUT_HN + 2ull * BATCH * HID)        // + 131,072

// fp32 -> bf16 bits, round-to-nearest-even
__device__ __forceinline__ short f2bf(float f) {
    unsigned int u = __builtin_bit_cast(unsigned int, f);
    u = (u + 0x7fffu + ((u >> 16) & 1u)) >> 16;
    return (short)u;
}
__device__ __forceinline__ s16x8 cvt8(const float* p) {
    s16x8 r;
#pragma unroll
    for (int j = 0; j < 8; ++j) r[j] = f2bf(p[j]);
    return r;
}

__global__ void __launch_bounds__(THREADS, 1)
lstm_enc(const int* __restrict__ src, const void* __restrict__ WembV,
         const void* __restrict__ WihV, const void* __restrict__ WhhV,
         const void* __restrict__ bihV, const void* __restrict__ bhhV,
         float* __restrict__ out, bf16* __restrict__ hbuf)
{
    __shared__ __align__(16) bf16 slab[NCOLS][ROWSTRIDE];   // 131,584 B (persists)
    __shared__ float gates[BATCH][NCOLS];                   // 8,192 B
    __shared__ float bias[NCOLS];
    __shared__ int   fp32flag;

    cg::grid_group grid = cg::this_grid();

    const int wg    = blockIdx.x;
    const int layer = wg >> 7;                 // WGs 0-127: layer0, 128-255: layer1
    const int j0    = (wg & 127) * UNITS;      // hidden-unit base
    const int tid   = threadIdx.x;
    const int lane  = tid & 63;
    const int wave  = tid >> 6;
    const int m     = lane & 15;               // frag row/col index
    const int kq    = (lane >> 4) * 8;         // k sub-offset within MFMA step
    const int b_a   = wave * 16 + m;           // batch row this lane loads for A

    // ---- runtime input-dtype sniff: fp32 data viewed as bf16 has wild exponents ----
    if (tid == 0) fp32flag = 0;
    __syncthreads();
    {
        const bf16* ev = (const bf16*)WembV;
        float v = __bfloat162float(ev[tid & 127]);
        if (fabsf(v) > 8.0f) atomicOr(&fp32flag, 1);
    }
    __syncthreads();
    const bool f32in = (fp32flag != 0);

    // ---- preamble: weight slab (rows = [i8|f8|g8|o8], K = [W_ih row | W_hh row]) ----
    for (int r = 0; r < NCOLS; ++r) {
        int g = r >> 3, u = r & 7;
        size_t grow = (size_t)layer * GATES * HID + (size_t)(g * HID + j0 + u) * HID;
        int k = tid * 8;                       // 256 threads x 8 = 2048 exact
        if (f32in) {
            const float* s = (k < HID) ? ((const float*)WihV + grow + k)
                                       : ((const float*)WhhV + grow + (k - HID));
            *(s16x8*)&slab[r][k] = cvt8(s);
        } else {
            const bf16* s = (k < HID) ? ((const bf16*)WihV + grow + k)
                                      : ((const bf16*)WhhV + grow + (k - HID));
            *(s16x8*)&slab[r][k] = *(const s16x8*)s;
        }
    }
    if (tid < NCOLS) {
        int g = tid >> 3, u = tid & 7;
        int off = layer * GATES + g * HID + j0 + u;
        bias[tid] = f32in
            ? (((const float*)bihV)[off] + ((const float*)bhhV)[off])
            : (__bfloat162float(((const bf16*)bihV)[off]) +
               __bfloat162float(((const bf16*)bhhV)[off]));
    }
    // ---- zero h double-buffers in ws (poisoned 0xAA before every launch) ----
    {
        int* hz = (int*)hbuf;
        const int total = 4 * BH / 2;          // h0[2]+h1[2] as ints = 512 KB
        for (int i = wg * THREADS + tid; i < total; i += NWG * THREADS) hz[i] = 0;
    }
    float c0s = 0.f, c1s = 0.f;                // c-state: (b = tid>>3 [+32], u = tid&7)

    grid.sync();

    bf16* h0 = hbuf;                           // [2][B][H] parity double-buffer
    bf16* h1 = hbuf + 2 * BH;

    // phase p: layer0 computes t=p (p<SEQ), layer1 computes t=p-1 (p>=1)
    for (int p = 0; p <= SEQ; ++p) {
        const bool active = (layer == 0) ? (p < SEQ) : (p >= 1);
        if (active) {
            const int t  = (layer == 0) ? p : (p - 1);
            const int rp = 1 - (p & 1);        // read parity
            const int wp = p & 1;              // write parity
            f32x4 acc0 = {0.f, 0.f, 0.f, 0.f};
            f32x4 acc1 = {0.f, 0.f, 0.f, 0.f};

            // ---- x @ W_ih^T ----
            if (layer == 0 && f32in) {
                const float* xF = (const float*)WembV + (size_t)src[b_a * SEQ + t] * HID;
#pragma unroll
                for (int kk = 0; kk < 32; ++kk) {
                    const int k = kk * 32 + kq;
                    s16x8 af = cvt8(xF + k);
                    s16x8 b0 = *(const s16x8*)&slab[m][k];
                    s16x8 b1 = *(const s16x8*)&slab[16 + m][k];
                    acc0 = __builtin_amdgcn_mfma_f32_16x16x32_bf16(af, b0, acc0, 0, 0, 0);
                    acc1 = __builtin_amdgcn_mfma_f32_16x16x32_bf16(af, b1, acc1, 0, 0, 0);
                }
            } else {
                const bf16* x = (layer == 0)
                    ? (const bf16*)WembV + (size_t)src[b_a * SEQ + t] * HID
                    : h0 + (size_t)rp * BH + b_a * HID;
#pragma unroll
                for (int kk = 0; kk < 32; ++kk) {
                    const int k = kk * 32 + kq;
                    s16x8 af = *(const s16x8*)(x + k);
                    s16x8 b0 = *(const s16x8*)&slab[m][k];
                    s16x8 b1 = *(const s16x8*)&slab[16 + m][k];
                    acc0 = __builtin_amdgcn_mfma_f32_16x16x32_bf16(af, b0, acc0, 0, 0, 0);
                    acc1 = __builtin_amdgcn_mfma_f32_16x16x32_bf16(af, b1, acc1, 0, 0, 0);
                }
            }
            // ---- h @ W_hh^T (h is internal bf16 always) ----
            {
                const bf16* hrow = ((layer == 0) ? h0 : h1) + (size_t)rp * BH + b_a * HID;
#pragma unroll
                for (int kk = 0; kk < 32; ++kk) {
                    const int k = kk * 32 + kq;
                    s16x8 af = *(const s16x8*)(hrow + k);
                    s16x8 b0 = *(const s16x8*)&slab[m][HID + k];
                    s16x8 b1 = *(const s16x8*)&slab[16 + m][HID + k];
                    acc0 = __builtin_amdgcn_mfma_f32_16x16x32_bf16(af, b0, acc0, 0, 0, 0);
                    acc1 = __builtin_amdgcn_mfma_f32_16x16x32_bf16(af, b1, acc1, 0, 0, 0);
                }
            }
            // C/D layout: col = lane&15, row = (lane>>4)*4 + r  (verified m89/m91)
            const int rowg = wave * 16 + (lane >> 4) * 4;
#pragma unroll
            for (int r = 0; r < 4; ++r) {
                gates[rowg + r][m]      = acc0[r];
                gates[rowg + r][16 + m] = acc1[r];
            }
            __syncthreads();
            bf16* hw = ((layer == 0) ? h0 : h1) + (size_t)wp * BH;
#pragma unroll
            for (int qq = 0; qq < 2; ++qq) {
                int q = tid + qq * THREADS;    // 512 (b,u) pairs, 2 per thread
                int bb = q >> 3, u = q & 7;
                float gi = gates[bb][u]      + bias[u];
                float gf = gates[bb][u + 8]  + bias[u + 8];
                float gg = gates[bb][u + 16] + bias[u + 16];
                float go = gates[bb][u + 24] + bias[u + 24];
                float si = 1.f / (1.f + __expf(-gi));
                float sf = 1.f / (1.f + __expf(-gf));
                float so = 1.f / (1.f + __expf(-go));
                float tg = tanhf(gg);
                float c  = sf * (qq ? c1s : c0s) + si * tg;
                if (qq) c1s = c; else c0s = c;
                float h  = so * tanhf(c);
                hw[bb * HID + j0 + u] = __float2bfloat16(h);   // internal state: bf16
                if (layer == 1)
                    out[((size_t)bb * SEQ + t) * HID + j0 + u] = h;   // fp32 output
                if (t == SEQ - 1) {
                    size_t o = ((size_t)layer * BATCH + bb) * HID + j0 + u;
                    out[OUT_HN + o] = h;                               // h_n fp32
                    out[OUT_CN + o] = c;                               // c_n fp32
                }
            }
        }
        grid.sync();
    }
}

extern "C" void kernel_launch(void* const* d_in, const int* in_sizes, int n_in,
                              void* d_out, int out_size, void* d_ws, size_t ws_size,
                              hipStream_t stream) {
    const int*  src  = (const int*)d_in[0];
    const void* emb  = d_in[1];
    const void* W_ih = d_in[2];
    const void* W_hh = d_in[3];
    const void* b_ih = d_in[4];
    const void* b_hh = d_in[5];
    float* out  = (float*)d_out;
    bf16*  hbuf = (bf16*)d_ws;                 // needs 512 KB

    void* args[] = {&src, &emb, &W_ih, &W_hh, &b_ih, &b_hh, &out, &hbuf};
    hipLaunchCooperativeKernel((void*)lstm_enc, dim3(NWG), dim3(THREADS),
                               args, 0, stream);
}

// Round 4
// 7742.319 us; speedup vs baseline: 1.7200x; 1.7200x over previous
//
#include <hip/hip_runtime.h>
#include <hip/hip_bf16.h>

typedef __hip_bfloat16 bf16;
typedef __attribute__((ext_vector_type(8))) short s16x8;   // 8 bf16 (MFMA A/B frag)
typedef __attribute__((ext_vector_type(4))) float f32x4;   // MFMA C/D frag

#define BATCH   64
#define SEQ     256
#define HID     1024
#define GATES   4096
#define NWG     256
#define THREADS 256
#define UNITS   8            // hidden units per WG
#define NCOLS   32           // gate columns per WG (4 gates x 8 units)
#define ROWSTRIDE 2056       // 2048 K + 8 pad elems (LDS bank de-alias)
#define GSTRIDE 33           // gates LDS row stride (+1 pad: stride-32 was 16-way conflicted)
#define BH      (BATCH * HID)

#define H0_SLOTS 4           // layer0 h ring (lets layer0 run ahead)
#define H1_SLOTS 2
#define FLAG_ELEMS ((size_t)6 * BH)            // flags start after h slots (bf16 elems)
#define WS_BYTES  (FLAG_ELEMS * 2 + 34 * 128)  // 786,432 + 4,352 = 790,784

#define OUT_HN  ((size_t)BATCH * SEQ * HID)
#define OUT_CN  (OUT_HN + 2ull * BATCH * HID)

// fp32 -> bf16 bits, round-to-nearest-even
__device__ __forceinline__ short f2bf(float f) {
    unsigned int u = __builtin_bit_cast(unsigned int, f);
    u = (u + 0x7fffu + ((u >> 16) & 1u)) >> 16;
    return (short)u;
}
__device__ __forceinline__ s16x8 cvt8(const float* p) {
    s16x8 r;
#pragma unroll
    for (int j = 0; j < 8; ++j) r[j] = f2bf(p[j]);
    return r;
}
// coherent-point (agent-scope, relaxed) 16B h-fragment load: bypasses stale per-XCD L2
__device__ __forceinline__ s16x8 ld16(bf16* p) {
    union { unsigned long long q[2]; s16x8 v; } u;
    u.q[0] = __hip_atomic_load((unsigned long long*)p,     __ATOMIC_RELAXED, __HIP_MEMORY_SCOPE_AGENT);
    u.q[1] = __hip_atomic_load((unsigned long long*)p + 1, __ATOMIC_RELAXED, __HIP_MEMORY_SCOPE_AGENT);
    return u.v;
}

__global__ void ws_init(unsigned int* p, int n) {
    for (int i = blockIdx.x * blockDim.x + threadIdx.x; i < n; i += gridDim.x * blockDim.x)
        p[i] = 0u;
}

__global__ void __launch_bounds__(THREADS, 1)
lstm_enc(const int* __restrict__ src, const float* __restrict__ Wemb,
         const float* __restrict__ Wih, const float* __restrict__ Whh,
         const float* __restrict__ bih, const float* __restrict__ bhh,
         float* __restrict__ out, bf16* __restrict__ hbuf)
{
    __shared__ __align__(16) bf16 slab[NCOLS][ROWSTRIDE];   // 131,584 B (persists)
    __shared__ float gates[BATCH][GSTRIDE];                 // 8,448 B
    __shared__ float bias[NCOLS];

    const int wg    = blockIdx.x;
    const int layer = wg >> 7;                 // 0-127: layer0, 128-255: layer1
    const int wgl   = wg & 127;
    const int j0    = wgl * UNITS;
    const int tid   = threadIdx.x;
    const int lane  = tid & 63;
    const int wave  = tid >> 6;
    const int m     = lane & 15;
    const int kq    = (lane >> 4) * 8;
    const int b_a   = wave * 16 + m;           // batch row this lane loads for A

    // ---- weight slab: rows = [i8|f8|g8|o8], K = [W_ih row | W_hh row], fp32->bf16 ----
    for (int r = 0; r < NCOLS; ++r) {
        int g = r >> 3, u = r & 7;
        size_t grow = (size_t)layer * GATES * HID + (size_t)(g * HID + j0 + u) * HID;
        int k = tid * 8;                       // 256 threads x 8 = 2048 exact
        const float* s = (k < HID) ? (Wih + grow + k) : (Whh + grow + (k - HID));
        *(s16x8*)&slab[r][k] = cvt8(s);
    }
    if (tid < NCOLS) {
        int g = tid >> 3, u = tid & 7;
        int off = layer * GATES + g * HID + j0 + u;
        bias[tid] = bih[off] + bhh[off];
    }
    __syncthreads();

    bf16* h0 = hbuf;                           // [4][B][H] ring
    bf16* h1 = hbuf + H0_SLOTS * BH;           // [2][B][H] ring
    unsigned int* flags = (unsigned int*)(hbuf + FLAG_ELEMS);
    // line i = flags + i*32 (128 B apart). 0-15: L0 groups, 16-31: L1 groups, 32/33: roots
    unsigned int* grp   = flags + (16 * layer + (wgl >> 3)) * 32;
    unsigned int* myrt  = flags + (32 + layer) * 32;
    unsigned int* Art   = flags + 32 * 32;     // layer0 completions x128
    unsigned int* Brt   = flags + 33 * 32;     // layer1 completions x128

    // epilogue mapping: thread -> (bb = tid>>2, u0 = 2*(tid&3)); c-state in registers
    const int bb = tid >> 2;
    const int u0 = (tid & 3) * 2;
    float c_lo = 0.f, c_hi = 0.f;

    for (int t = 0; t < SEQ; ++t) {
        // ---- wait: epoch counters (monotonic). layer0 needs A>=128t, B>=128(t-3);
        //      layer1 needs A>=128(t+1), B>=128t ----
        if (tid == 0) {
            int tgtA = (layer == 0) ? 128 * t : 128 * (t + 1);
            int tgtB = (layer == 0) ? 128 * (t - 3) : 128 * t;
            if (tgtA > 0)
                while ((int)__hip_atomic_load(Art, __ATOMIC_RELAXED, __HIP_MEMORY_SCOPE_AGENT) < tgtA)
                    __builtin_amdgcn_s_sleep(4);
            if (tgtB > 0)
                while ((int)__hip_atomic_load(Brt, __ATOMIC_RELAXED, __HIP_MEMORY_SCOPE_AGENT) < tgtB)
                    __builtin_amdgcn_s_sleep(4);
        }
        __syncthreads();

        f32x4 acc0 = {0.f, 0.f, 0.f, 0.f};
        f32x4 acc1 = {0.f, 0.f, 0.f, 0.f};

        // ---- x @ W_ih^T ----
        if (layer == 0) {
            const float* xF = Wemb + (size_t)src[b_a * SEQ + t] * HID;
#pragma unroll
            for (int kk = 0; kk < 32; ++kk) {
                const int k = kk * 32 + kq;
                s16x8 af = cvt8(xF + k);
                s16x8 b0 = *(const s16x8*)&slab[m][k];
                s16x8 b1 = *(const s16x8*)&slab[16 + m][k];
                acc0 = __builtin_amdgcn_mfma_f32_16x16x32_bf16(af, b0, acc0, 0, 0, 0);
                acc1 = __builtin_amdgcn_mfma_f32_16x16x32_bf16(af, b1, acc1, 0, 0, 0);
            }
        } else {
            bf16* xrow = h0 + (size_t)(t & (H0_SLOTS - 1)) * BH + b_a * HID;
#pragma unroll
            for (int kk = 0; kk < 32; ++kk) {
                const int k = kk * 32 + kq;
                s16x8 af = ld16(xrow + k);
                s16x8 b0 = *(const s16x8*)&slab[m][k];
                s16x8 b1 = *(const s16x8*)&slab[16 + m][k];
                acc0 = __builtin_amdgcn_mfma_f32_16x16x32_bf16(af, b0, acc0, 0, 0, 0);
                acc1 = __builtin_amdgcn_mfma_f32_16x16x32_bf16(af, b1, acc1, 0, 0, 0);
            }
        }
        // ---- h @ W_hh^T ----
        {
            bf16* hrow = ((layer == 0)
                ? h0 + (size_t)((t - 1) & (H0_SLOTS - 1)) * BH
                : h1 + (size_t)((t - 1) & (H1_SLOTS - 1)) * BH) + b_a * HID;
#pragma unroll
            for (int kk = 0; kk < 32; ++kk) {
                const int k = kk * 32 + kq;
                s16x8 af = ld16(hrow + k);
                s16x8 b0 = *(const s16x8*)&slab[m][HID + k];
                s16x8 b1 = *(const s16x8*)&slab[16 + m][HID + k];
                acc0 = __builtin_amdgcn_mfma_f32_16x16x32_bf16(af, b0, acc0, 0, 0, 0);
                acc1 = __builtin_amdgcn_mfma_f32_16x16x32_bf16(af, b1, acc1, 0, 0, 0);
            }
        }
        // C/D layout: col = lane&15, row = (lane>>4)*4 + r  (verified m89/m91)
        const int rowg = wave * 16 + (lane >> 4) * 4;
#pragma unroll
        for (int r = 0; r < 4; ++r) {
            gates[rowg + r][m]      = acc0[r];
            gates[rowg + r][16 + m] = acc1[r];
        }
        __syncthreads();

        // ---- epilogue: 2 adjacent units per thread, c-state in registers ----
        {
            float gi0 = gates[bb][u0]      + bias[u0];
            float gi1 = gates[bb][u0 + 1]  + bias[u0 + 1];
            float gf0 = gates[bb][u0 + 8]  + bias[u0 + 8];
            float gf1 = gates[bb][u0 + 9]  + bias[u0 + 9];
            float gg0 = gates[bb][u0 + 16] + bias[u0 + 16];
            float gg1 = gates[bb][u0 + 17] + bias[u0 + 17];
            float go0 = gates[bb][u0 + 24] + bias[u0 + 24];
            float go1 = gates[bb][u0 + 25] + bias[u0 + 25];
            float si0 = 1.f / (1.f + __expf(-gi0)), si1 = 1.f / (1.f + __expf(-gi1));
            float sf0 = 1.f / (1.f + __expf(-gf0)), sf1 = 1.f / (1.f + __expf(-gf1));
            float so0 = 1.f / (1.f + __expf(-go0)), so1 = 1.f / (1.f + __expf(-go1));
            float tg0 = tanhf(gg0), tg1 = tanhf(gg1);
            c_lo = sf0 * c_lo + si0 * tg0;
            c_hi = sf1 * c_hi + si1 * tg1;
            float h_lo = so0 * tanhf(c_lo);
            float h_hi = so1 * tanhf(c_hi);

            bf16* hw = ((layer == 0) ? h0 + (size_t)(t & (H0_SLOTS - 1)) * BH
                                     : h1 + (size_t)(t & (H1_SLOTS - 1)) * BH);
            unsigned int hp = (unsigned int)(unsigned short)f2bf(h_lo) |
                              ((unsigned int)(unsigned short)f2bf(h_hi) << 16);
            __hip_atomic_store((unsigned int*)(hw + bb * HID + j0 + u0), hp,
                               __ATOMIC_RELAXED, __HIP_MEMORY_SCOPE_AGENT);
            if (layer == 1) {
                float2 hv = make_float2(h_lo, h_hi);
                *(float2*)(out + ((size_t)bb * SEQ + t) * HID + j0 + u0) = hv;
            }
            if (t == SEQ - 1) {
                size_t o = ((size_t)layer * BATCH + bb) * HID + j0 + u0;
                *(float2*)(out + OUT_HN + o) = make_float2(h_lo, h_hi);
                *(float2*)(out + OUT_CN + o) = make_float2(c_lo, c_hi);
            }
        }
        __syncthreads();   // drains vmcnt(0): all h stores at coherent point
        if (tid == 0) {
            unsigned prev = __hip_atomic_fetch_add(grp, 1u, __ATOMIC_RELAXED, __HIP_MEMORY_SCOPE_AGENT);
            if ((prev & 7u) == 7u)  // last of 8-WG group -> promote to root
                __hip_atomic_fetch_add(myrt, 8u, __ATOMIC_RELAXED, __HIP_MEMORY_SCOPE_AGENT);
        }
    }
}

extern "C" void kernel_launch(void* const* d_in, const int* in_sizes, int n_in,
                              void* d_out, int out_size, void* d_ws, size_t ws_size,
                              hipStream_t stream) {
    const int*   src  = (const int*)d_in[0];
    const float* emb  = (const float*)d_in[1];
    const float* W_ih = (const float*)d_in[2];
    const float* W_hh = (const float*)d_in[3];
    const float* b_ih = (const float*)d_in[4];
    const float* b_hh = (const float*)d_in[5];
    float* out  = (float*)d_out;
    bf16*  hbuf = (bf16*)d_ws;                 // uses 790,784 B

    // zero h rings + flag lines (ws is re-poisoned 0xAA before every replay)
    unsigned int* wsp = (unsigned int*)d_ws;
    int n = (int)(WS_BYTES / 4);
    ws_init<<<256, 256, 0, stream>>>(wsp, n);

    void* args[] = {&src, &emb, &W_ih, &W_hh, &b_ih, &b_hh, &out, &hbuf};
    hipLaunchCooperativeKernel((void*)lstm_enc, dim3(NWG), dim3(THREADS),
                               args, 0, stream);
}